// Round 1
// baseline (2207.468 us; speedup 1.0000x reference)
//
#include <hip/hip_runtime.h>
#include <stdint.h>

typedef _Float16 half2v __attribute__((ext_vector_type(2)));

__device__ __forceinline__ float sigf(float x) {
    return __builtin_amdgcn_rcpf(1.0f + __expf(-x));
}
__device__ __forceinline__ float tanhf_fast(float x) {
    return 1.0f - 2.0f * __builtin_amdgcn_rcpf(1.0f + __expf(2.0f * x));
}
__device__ __forceinline__ uint32_t pk2(float a, float b) {
    uint16_t ua = __builtin_bit_cast(uint16_t, (_Float16)a);
    uint16_t ub = __builtin_bit_cast(uint16_t, (_Float16)b);
    return (uint32_t)ua | ((uint32_t)ub << 16);
}
__device__ __forceinline__ float f16u(uint16_t b) {
    return (float)__builtin_bit_cast(_Float16, b);
}
__device__ __forceinline__ float dot2(uint32_t w, uint32_t h, float acc) {
#if __has_builtin(__builtin_amdgcn_fdot2)
    return __builtin_amdgcn_fdot2(__builtin_bit_cast(half2v, w),
                                  __builtin_bit_cast(half2v, h), acc, false);
#else
    asm("v_fma_mix_f32 %0, %1, %2, %0 op_sel:[0,0,0] op_sel_hi:[1,1,0]"
        : "+v"(acc) : "v"(w), "v"(h));
    asm("v_fma_mix_f32 %0, %1, %2, %0 op_sel:[1,1,0] op_sel_hi:[1,1,0]"
        : "+v"(acc) : "v"(w), "v"(h));
    return acc;
#endif
}

#define DOT4(acc, wv, hv)            \
    acc = dot2(wv.x, hv.x, acc);     \
    acc = dot2(wv.y, hv.y, acc);     \
    acc = dot2(wv.z, hv.z, acc);     \
    acc = dot2(wv.w, hv.w, acc);

// Fused 2-layer LSTM encoder (persistent, T=1024) + decoder tail.
// grid = 256 blocks (1/CU), block = 256 thr (4 waves).
// Matmul role: wave w computes gate rows [w*64, w*64+64) for the block's 4 samples.
// Update role: thread (j = tid&63, sq = tid>>6) owns unit j of sample sq.
__global__ __launch_bounds__(256, 1)
void lstm_fused(const float* __restrict__ x,
                const float* __restrict__ W1i, const float* __restrict__ W1h,
                const float* __restrict__ b1i, const float* __restrict__ b1h,
                const float* __restrict__ W2i, const float* __restrict__ W2h,
                const float* __restrict__ b2i, const float* __restrict__ b2h,
                const float* __restrict__ eW,  const float* __restrict__ eb,
                const float* __restrict__ D1i, const float* __restrict__ D1bi,
                const float* __restrict__ D1bh,
                const float* __restrict__ D2i, const float* __restrict__ D2bi,
                const float* __restrict__ D2bh,
                const float* __restrict__ dW,  const float* __restrict__ db,
                float* __restrict__ out)
{
    __shared__ uint4 W1P[8][256];    // Whh1, f16x8 packed per (k8, row)   32 KB
    __shared__ uint4 W2P[16][256];   // [Wih2 | Whh2], f16x8 packed        64 KB
    __shared__ uint32_t h1L[4][32];  // h1 per sample, f16 pairs
    __shared__ uint32_t h2L[4][32];  // h2 per sample, f16 pairs
    __shared__ float preL[4][260];   // preacts [sample][row] (+pad)
    __shared__ float uL[4][8];

    const int tid = threadIdx.x;
    const int blk = blockIdx.x;
    const int r  = tid;        // matmul gate-row
    const int j  = tid & 63;   // update unit
    const int sq = tid >> 6;   // update sample (== wave id)

    // ---- stage packed f16 weights into LDS ----
    for (int idx = tid; idx < 8 * 256; idx += 256) {
        int k8 = idx >> 8, rr = idx & 255;
        const float* s = W1h + rr * 64 + k8 * 8;
        uint4 p;
        p.x = pk2(s[0], s[1]); p.y = pk2(s[2], s[3]);
        p.z = pk2(s[4], s[5]); p.w = pk2(s[6], s[7]);
        W1P[k8][rr] = p;
    }
    for (int idx = tid; idx < 16 * 256; idx += 256) {
        int k8 = idx >> 8, rr = idx & 255;
        const float* s = (k8 < 8) ? (W2i + rr * 64 + k8 * 8)
                                  : (W2h + rr * 64 + (k8 - 8) * 8);
        uint4 p;
        p.x = pk2(s[0], s[1]); p.y = pk2(s[2], s[3]);
        p.z = pk2(s[4], s[5]); p.w = pk2(s[6], s[7]);
        W2P[k8][rr] = p;
    }
    if (tid < 128) {
        h1L[tid >> 5][tid & 31] = 0u;
        h2L[tid >> 5][tid & 31] = 0u;
    }

    const float bias1 = b1i[r] + b1h[r];
    const float bias2 = b2i[r] + b2h[r];
    const float wx0 = W1i[r * 3 + 0], wx1 = W1i[r * 3 + 1], wx2 = W1i[r * 3 + 2];

    float c1 = 0.0f, c2 = 0.0f;

    size_t xbase0 = ((size_t)(blk * 4 + 0) * 1024) * 3;
    size_t xbase1 = ((size_t)(blk * 4 + 1) * 1024) * 3;
    size_t xbase2 = ((size_t)(blk * 4 + 2) * 1024) * 3;
    size_t xbase3 = ((size_t)(blk * 4 + 3) * 1024) * 3;
    float xa00 = x[xbase0+0], xa01 = x[xbase0+1], xa02 = x[xbase0+2];
    float xa10 = x[xbase1+0], xa11 = x[xbase1+1], xa12 = x[xbase1+2];
    float xa20 = x[xbase2+0], xa21 = x[xbase2+1], xa22 = x[xbase2+2];
    float xa30 = x[xbase3+0], xa31 = x[xbase3+1], xa32 = x[xbase3+2];

    __syncthreads();

    #pragma unroll 1
    for (int t = 0; t < 1024; ++t) {
        // ---- Phase A: layer1 matmul (rows r, 4 samples) ----
        float a0 = bias1 + wx0 * xa00 + wx1 * xa01 + wx2 * xa02;
        float a1 = bias1 + wx0 * xa10 + wx1 * xa11 + wx2 * xa12;
        float a2 = bias1 + wx0 * xa20 + wx1 * xa21 + wx2 * xa22;
        float a3 = bias1 + wx0 * xa30 + wx1 * xa31 + wx2 * xa32;
        #pragma unroll
        for (int k8 = 0; k8 < 8; ++k8) {
            const uint4 wv = W1P[k8][r];
            const uint4 hv0 = *(const uint4*)&h1L[0][k8 * 4];
            const uint4 hv1 = *(const uint4*)&h1L[1][k8 * 4];
            const uint4 hv2 = *(const uint4*)&h1L[2][k8 * 4];
            const uint4 hv3 = *(const uint4*)&h1L[3][k8 * 4];
            DOT4(a0, wv, hv0) DOT4(a1, wv, hv1) DOT4(a2, wv, hv2) DOT4(a3, wv, hv3)
        }
        preL[0][r] = a0; preL[1][r] = a1; preL[2][r] = a2; preL[3][r] = a3;
        __syncthreads();

        // ---- Phase B: layer1 update + prefetch x(t+1) ----
        int tn = (t < 1023) ? (t + 1) : t;
        const float* p0 = x + xbase0 + (size_t)tn * 3;
        const float* p1 = x + xbase1 + (size_t)tn * 3;
        const float* p2 = x + xbase2 + (size_t)tn * 3;
        const float* p3 = x + xbase3 + (size_t)tn * 3;
        float xb00 = p0[0], xb01 = p0[1], xb02 = p0[2];
        float xb10 = p1[0], xb11 = p1[1], xb12 = p1[2];
        float xb20 = p2[0], xb21 = p2[1], xb22 = p2[2];
        float xb30 = p3[0], xb31 = p3[1], xb32 = p3[2];
        {
            float pi = preL[sq][j],       pf = preL[sq][64 + j];
            float pg = preL[sq][128 + j], po = preL[sq][192 + j];
            c1 = sigf(pf) * c1 + sigf(pi) * tanhf_fast(pg);
            float hn = sigf(po) * tanhf_fast(c1);
            ((uint16_t*)h1L[sq])[j] = __builtin_bit_cast(uint16_t, (_Float16)hn);
        }
        __syncthreads();

        // ---- Phase C: layer2 matmul over [h1 ; h2] ----
        a0 = bias2; a1 = bias2; a2 = bias2; a3 = bias2;
        #pragma unroll
        for (int k8 = 0; k8 < 16; ++k8) {
            const uint4 wv = W2P[k8][r];
            uint4 hv0, hv1, hv2, hv3;
            if (k8 < 8) {
                hv0 = *(const uint4*)&h1L[0][k8 * 4];
                hv1 = *(const uint4*)&h1L[1][k8 * 4];
                hv2 = *(const uint4*)&h1L[2][k8 * 4];
                hv3 = *(const uint4*)&h1L[3][k8 * 4];
            } else {
                hv0 = *(const uint4*)&h2L[0][(k8 - 8) * 4];
                hv1 = *(const uint4*)&h2L[1][(k8 - 8) * 4];
                hv2 = *(const uint4*)&h2L[2][(k8 - 8) * 4];
                hv3 = *(const uint4*)&h2L[3][(k8 - 8) * 4];
            }
            DOT4(a0, wv, hv0) DOT4(a1, wv, hv1) DOT4(a2, wv, hv2) DOT4(a3, wv, hv3)
        }
        preL[0][r] = a0; preL[1][r] = a1; preL[2][r] = a2; preL[3][r] = a3;
        __syncthreads();

        // ---- Phase D: layer2 update ----
        {
            float pi = preL[sq][j],       pf = preL[sq][64 + j];
            float pg = preL[sq][128 + j], po = preL[sq][192 + j];
            c2 = sigf(pf) * c2 + sigf(pi) * tanhf_fast(pg);
            float hn = sigf(po) * tanhf_fast(c2);
            ((uint16_t*)h2L[sq])[j] = __builtin_bit_cast(uint16_t, (_Float16)hn);
        }
        xa00 = xb00; xa01 = xb01; xa02 = xb02;
        xa10 = xb10; xa11 = xb11; xa12 = xb12;
        xa20 = xb20; xa21 = xb21; xa22 = xb22;
        xa30 = xb30; xa31 = xb31; xa32 = xb32;
        __syncthreads();
    }

    // ---- Decoder tail: wave sq handles sample S ----
    const int S = blk * 4 + sq;

    // u = enc_fc(h2_final)
    if (j < 5) {
        float acc = eb[j];
        const uint16_t* hh = (const uint16_t*)h2L[sq];
        for (int k = 0; k < 64; ++k) acc += eW[j * 64 + k] * f16u(hh[k]);
        uL[sq][j] = acc;
        out[S * 5 + j] = acc;
    }
    __syncthreads();

    // d1: single step from zero state -> only gates i(0), g(2), o(3) matter
    {
        float u0 = uL[sq][0], u1 = uL[sq][1], u2 = uL[sq][2], u3 = uL[sq][3], u4 = uL[sq][4];
        int ri = j, rg = 128 + j, ro = 192 + j;
        float pi = D1bi[ri] + D1bh[ri];
        float pg = D1bi[rg] + D1bh[rg];
        float po = D1bi[ro] + D1bh[ro];
        pi += D1i[ri*5+0]*u0 + D1i[ri*5+1]*u1 + D1i[ri*5+2]*u2 + D1i[ri*5+3]*u3 + D1i[ri*5+4]*u4;
        pg += D1i[rg*5+0]*u0 + D1i[rg*5+1]*u1 + D1i[rg*5+2]*u2 + D1i[rg*5+3]*u3 + D1i[rg*5+4]*u4;
        po += D1i[ro*5+0]*u0 + D1i[ro*5+1]*u1 + D1i[ro*5+2]*u2 + D1i[ro*5+3]*u3 + D1i[ro*5+4]*u4;
        float cd = sigf(pi) * tanhf_fast(pg);
        float hd = sigf(po) * tanhf_fast(cd);
        preL[sq][j] = hd;
    }
    __syncthreads();

    // d2: single step from zero state
    {
        int ri = j, rg = 128 + j, ro = 192 + j;
        float pi = D2bi[ri] + D2bh[ri];
        float pg = D2bi[rg] + D2bh[rg];
        float po = D2bi[ro] + D2bh[ro];
        for (int k = 0; k < 64; ++k) {
            float hk = preL[sq][k];
            pi += D2i[ri * 64 + k] * hk;
            pg += D2i[rg * 64 + k] * hk;
            po += D2i[ro * 64 + k] * hk;
        }
        float cd = sigf(pi) * tanhf_fast(pg);
        float hd = sigf(po) * tanhf_fast(cd);
        preL[sq][128 + j] = hd;
    }
    __syncthreads();

    // tau = dec_fc(h_d2)
    if (j < 3) {
        float acc = db[j];
        for (int k = 0; k < 64; ++k) acc += dW[j * 64 + k] * preL[sq][128 + k];
        out[5120 + S * 3 + j] = acc;
    }
}

extern "C" void kernel_launch(void* const* d_in, const int* in_sizes, int n_in,
                              void* d_out, int out_size, void* d_ws, size_t ws_size,
                              hipStream_t stream) {
    (void)in_sizes; (void)n_in; (void)out_size; (void)d_ws; (void)ws_size;
    const float* x    = (const float*)d_in[0];
    const float* W1i  = (const float*)d_in[1];
    const float* W1h  = (const float*)d_in[2];
    const float* b1i  = (const float*)d_in[3];
    const float* b1h  = (const float*)d_in[4];
    const float* W2i  = (const float*)d_in[5];
    const float* W2h  = (const float*)d_in[6];
    const float* b2i  = (const float*)d_in[7];
    const float* b2h  = (const float*)d_in[8];
    const float* eW   = (const float*)d_in[9];
    const float* eb   = (const float*)d_in[10];
    const float* D1i  = (const float*)d_in[11];
    const float* D1bi = (const float*)d_in[13];
    const float* D1bh = (const float*)d_in[14];
    const float* D2i  = (const float*)d_in[15];
    const float* D2bi = (const float*)d_in[17];
    const float* D2bh = (const float*)d_in[18];
    const float* dW   = (const float*)d_in[19];
    const float* db   = (const float*)d_in[20];

    hipLaunchKernelGGL(lstm_fused, dim3(256), dim3(256), 0, stream,
                       x, W1i, W1h, b1i, b1h, W2i, W2h, b2i, b2h, eW, eb,
                       D1i, D1bi, D1bh, D2i, D2bi, D2bh, dW, db,
                       (float*)d_out);
}

// Round 2
// 1666.715 us; speedup vs baseline: 1.3244x; 1.3244x over previous
//
#include <hip/hip_runtime.h>
#include <stdint.h>

typedef _Float16 half2v __attribute__((ext_vector_type(2)));

__device__ __forceinline__ float sigf(float x) {
    return __builtin_amdgcn_rcpf(1.0f + __expf(-x));
}
__device__ __forceinline__ float tanhf_fast(float x) {
    return 1.0f - 2.0f * __builtin_amdgcn_rcpf(1.0f + __expf(2.0f * x));
}
__device__ __forceinline__ uint32_t pk2(float a, float b) {
    uint16_t ua = __builtin_bit_cast(uint16_t, (_Float16)a);
    uint16_t ub = __builtin_bit_cast(uint16_t, (_Float16)b);
    return (uint32_t)ua | ((uint32_t)ub << 16);
}
__device__ __forceinline__ float f16u(uint16_t b) {
    return (float)__builtin_bit_cast(_Float16, b);
}
__device__ __forceinline__ float dot2(uint32_t w, uint32_t h, float acc) {
#if __has_builtin(__builtin_amdgcn_fdot2)
    return __builtin_amdgcn_fdot2(__builtin_bit_cast(half2v, w),
                                  __builtin_bit_cast(half2v, h), acc, false);
#else
    asm("v_fma_mix_f32 %0, %1, %2, %0 op_sel:[0,0,0] op_sel_hi:[1,1,0]"
        : "+v"(acc) : "v"(w), "v"(h));
    asm("v_fma_mix_f32 %0, %1, %2, %0 op_sel:[1,1,0] op_sel_hi:[1,1,0]"
        : "+v"(acc) : "v"(w), "v"(h));
    return acc;
#endif
}

#define DOT4(acc, wv, hv)            \
    acc = dot2(wv.x, hv.x, acc);     \
    acc = dot2(wv.y, hv.y, acc);     \
    acc = dot2(wv.z, hv.z, acc);     \
    acc = dot2(wv.w, hv.w, acc);

__device__ __forceinline__ uint4 pack8(const float* s) {
    uint4 p;
    p.x = pk2(s[0], s[1]); p.y = pk2(s[2], s[3]);
    p.z = pk2(s[4], s[5]); p.w = pk2(s[6], s[7]);
    return p;
}

// Fused 2-layer LSTM encoder (persistent, T=1024) + decoder tail.
// grid = 256 blocks (1/CU), block = 512 thr (8 waves -> 2 waves/SIMD).
// Thread (g = tid>>8, r = tid&255) owns gate row r's weights IN REGISTERS
// and computes rows for samples {2g, 2g+1}. Update role: threads 0..255,
// (j = tid&63, sq = tid>>6) own unit j of sample sq.
__global__ __launch_bounds__(512, 2)
void lstm_fused(const float* __restrict__ x,
                const float* __restrict__ W1i, const float* __restrict__ W1h,
                const float* __restrict__ b1i, const float* __restrict__ b1h,
                const float* __restrict__ W2i, const float* __restrict__ W2h,
                const float* __restrict__ b2i, const float* __restrict__ b2h,
                const float* __restrict__ eW,  const float* __restrict__ eb,
                const float* __restrict__ D1i, const float* __restrict__ D1bi,
                const float* __restrict__ D1bh,
                const float* __restrict__ D2i, const float* __restrict__ D2bi,
                const float* __restrict__ D2bh,
                const float* __restrict__ dW,  const float* __restrict__ db,
                float* __restrict__ out)
{
    __shared__ uint32_t h1L[4][32];  // h1 per sample, f16 pairs
    __shared__ uint32_t h2L[4][32];  // h2 per sample, f16 pairs
    __shared__ float preL[4][260];   // preacts [sample][row] (+pad)
    __shared__ float uL[4][8];

    const int tid = threadIdx.x;
    const int blk = blockIdx.x;
    const int g  = tid >> 8;   // sample-pair group
    const int r  = tid & 255;  // gate row
    const int s0 = 2 * g, s1 = 2 * g + 1;
    const int j  = tid & 63;   // update unit
    const int sq = tid >> 6;   // update sample (threads 0..255)

    // ---- pack this row's weights into registers (f16 pairs) ----
    uint4 w1q[8], w2q[8], w3q[8];
    #pragma unroll
    for (int k8 = 0; k8 < 8; ++k8) {
        w1q[k8] = pack8(W1h + r * 64 + k8 * 8);   // Whh1[r,:]
        w2q[k8] = pack8(W2i + r * 64 + k8 * 8);   // Wih2[r,:]
        w3q[k8] = pack8(W2h + r * 64 + k8 * 8);   // Whh2[r,:]
    }
    const float bias1 = b1i[r] + b1h[r];
    const float bias2 = b2i[r] + b2h[r];
    const float wx0 = W1i[r * 3 + 0], wx1 = W1i[r * 3 + 1], wx2 = W1i[r * 3 + 2];

    if (tid < 128) {
        h1L[tid >> 5][tid & 31] = 0u;
        h2L[tid >> 5][tid & 31] = 0u;
    }

    float c1 = 0.0f, c2 = 0.0f;  // state owned by threads 0..255

    const size_t xb0 = ((size_t)(blk * 4 + s0) * 1024) * 3;
    const size_t xb1 = ((size_t)(blk * 4 + s1) * 1024) * 3;
    float xa00 = x[xb0 + 0], xa01 = x[xb0 + 1], xa02 = x[xb0 + 2];
    float xa10 = x[xb1 + 0], xa11 = x[xb1 + 1], xa12 = x[xb1 + 2];

    __syncthreads();

    #pragma unroll 1
    for (int t = 0; t < 1024; ++t) {
        // ---- Phase A: layer1 matmul + layer2 h2-half (old h2), 2 samples ----
        float a0 = bias1 + wx0 * xa00 + wx1 * xa01 + wx2 * xa02;
        float a1 = bias1 + wx0 * xa10 + wx1 * xa11 + wx2 * xa12;
        float p0 = bias2, p1 = bias2;
        #pragma unroll
        for (int k8 = 0; k8 < 8; ++k8) {
            const uint4 hA0 = *(const uint4*)&h1L[s0][k8 * 4];
            const uint4 hA1 = *(const uint4*)&h1L[s1][k8 * 4];
            const uint4 hB0 = *(const uint4*)&h2L[s0][k8 * 4];
            const uint4 hB1 = *(const uint4*)&h2L[s1][k8 * 4];
            DOT4(a0, w1q[k8], hA0) DOT4(a1, w1q[k8], hA1)
            DOT4(p0, w3q[k8], hB0) DOT4(p1, w3q[k8], hB1)
        }
        preL[s0][r] = a0; preL[s1][r] = a1;
        __syncthreads();

        // ---- Phase B: layer1 update (threads 0..255) + x prefetch (all) ----
        int tn = (t < 1023) ? (t + 1) : t;
        const float* q0 = x + xb0 + (size_t)tn * 3;
        const float* q1 = x + xb1 + (size_t)tn * 3;
        float xn00 = q0[0], xn01 = q0[1], xn02 = q0[2];
        float xn10 = q1[0], xn11 = q1[1], xn12 = q1[2];
        if (tid < 256) {
            float pi = preL[sq][j],       pf = preL[sq][64 + j];
            float pg = preL[sq][128 + j], po = preL[sq][192 + j];
            c1 = sigf(pf) * c1 + sigf(pi) * tanhf_fast(pg);
            float hn = sigf(po) * tanhf_fast(c1);
            ((uint16_t*)h1L[sq])[j] = __builtin_bit_cast(uint16_t, (_Float16)hn);
        }
        __syncthreads();

        // ---- Phase C: layer2 h1-half (new h1) ----
        #pragma unroll
        for (int k8 = 0; k8 < 8; ++k8) {
            const uint4 hA0 = *(const uint4*)&h1L[s0][k8 * 4];
            const uint4 hA1 = *(const uint4*)&h1L[s1][k8 * 4];
            DOT4(p0, w2q[k8], hA0) DOT4(p1, w2q[k8], hA1)
        }
        preL[s0][r] = p0; preL[s1][r] = p1;
        __syncthreads();

        // ---- Phase D: layer2 update ----
        if (tid < 256) {
            float pi = preL[sq][j],       pf = preL[sq][64 + j];
            float pg = preL[sq][128 + j], po = preL[sq][192 + j];
            c2 = sigf(pf) * c2 + sigf(pi) * tanhf_fast(pg);
            float hn = sigf(po) * tanhf_fast(c2);
            ((uint16_t*)h2L[sq])[j] = __builtin_bit_cast(uint16_t, (_Float16)hn);
        }
        xa00 = xn00; xa01 = xn01; xa02 = xn02;
        xa10 = xn10; xa11 = xn11; xa12 = xn12;
        __syncthreads();
    }

    // ---- Decoder tail: threads 0..255, wave sq handles sample S ----
    const int S = blk * 4 + sq;

    // u = enc_fc(h2_final)
    if (tid < 256 && j < 5) {
        float acc = eb[j];
        const uint16_t* hh = (const uint16_t*)h2L[sq];
        for (int k = 0; k < 64; ++k) acc += eW[j * 64 + k] * f16u(hh[k]);
        uL[sq][j] = acc;
        out[S * 5 + j] = acc;
    }
    __syncthreads();

    // d1: single step from zero state -> only gates i(0), g(2), o(3) matter
    if (tid < 256) {
        float u0 = uL[sq][0], u1 = uL[sq][1], u2 = uL[sq][2], u3 = uL[sq][3], u4 = uL[sq][4];
        int ri = j, rg = 128 + j, ro = 192 + j;
        float pi = D1bi[ri] + D1bh[ri];
        float pg = D1bi[rg] + D1bh[rg];
        float po = D1bi[ro] + D1bh[ro];
        pi += D1i[ri*5+0]*u0 + D1i[ri*5+1]*u1 + D1i[ri*5+2]*u2 + D1i[ri*5+3]*u3 + D1i[ri*5+4]*u4;
        pg += D1i[rg*5+0]*u0 + D1i[rg*5+1]*u1 + D1i[rg*5+2]*u2 + D1i[rg*5+3]*u3 + D1i[rg*5+4]*u4;
        po += D1i[ro*5+0]*u0 + D1i[ro*5+1]*u1 + D1i[ro*5+2]*u2 + D1i[ro*5+3]*u3 + D1i[ro*5+4]*u4;
        float cd = sigf(pi) * tanhf_fast(pg);
        float hd = sigf(po) * tanhf_fast(cd);
        preL[sq][j] = hd;
    }
    __syncthreads();

    // d2: single step from zero state
    if (tid < 256) {
        int ri = j, rg = 128 + j, ro = 192 + j;
        float pi = D2bi[ri] + D2bh[ri];
        float pg = D2bi[rg] + D2bh[rg];
        float po = D2bi[ro] + D2bh[ro];
        for (int k = 0; k < 64; ++k) {
            float hk = preL[sq][k];
            pi += D2i[ri * 64 + k] * hk;
            pg += D2i[rg * 64 + k] * hk;
            po += D2i[ro * 64 + k] * hk;
        }
        float cd = sigf(pi) * tanhf_fast(pg);
        float hd = sigf(po) * tanhf_fast(cd);
        preL[sq][128 + j] = hd;
    }
    __syncthreads();

    // tau = dec_fc(h_d2)
    if (tid < 256 && j < 3) {
        float acc = db[j];
        for (int k = 0; k < 64; ++k) acc += dW[j * 64 + k] * preL[sq][128 + k];
        out[5120 + S * 3 + j] = acc;
    }
}

extern "C" void kernel_launch(void* const* d_in, const int* in_sizes, int n_in,
                              void* d_out, int out_size, void* d_ws, size_t ws_size,
                              hipStream_t stream) {
    (void)in_sizes; (void)n_in; (void)out_size; (void)d_ws; (void)ws_size;
    const float* x    = (const float*)d_in[0];
    const float* W1i  = (const float*)d_in[1];
    const float* W1h  = (const float*)d_in[2];
    const float* b1i  = (const float*)d_in[3];
    const float* b1h  = (const float*)d_in[4];
    const float* W2i  = (const float*)d_in[5];
    const float* W2h  = (const float*)d_in[6];
    const float* b2i  = (const float*)d_in[7];
    const float* b2h  = (const float*)d_in[8];
    const float* eW   = (const float*)d_in[9];
    const float* eb   = (const float*)d_in[10];
    const float* D1i  = (const float*)d_in[11];
    const float* D1bi = (const float*)d_in[13];
    const float* D1bh = (const float*)d_in[14];
    const float* D2i  = (const float*)d_in[15];
    const float* D2bi = (const float*)d_in[17];
    const float* D2bh = (const float*)d_in[18];
    const float* dW   = (const float*)d_in[19];
    const float* db   = (const float*)d_in[20];

    hipLaunchKernelGGL(lstm_fused, dim3(256), dim3(512), 0, stream,
                       x, W1i, W1h, b1i, b1h, W2i, W2h, b2i, b2h, eW, eb,
                       D1i, D1bi, D1bh, D2i, D2bi, D2bh, dW, db,
                       (float*)d_out);
}